// Round 13
// baseline (228.812 us; speedup 1.0000x reference)
//
#include <hip/hip_runtime.h>
#include <hip/hip_bf16.h>

// EGCL (EGNN layer): N=384 nodes, V=32 vectors, H=128 feats, U=256 width.
// E = N*(N-1) = 147072 fully-connected edges. f32 in/out, bf16 MFMA compute.
// Edges grouped by RECEIVER r (s=(r+1+j')%N): segment sums are in-block
// reductions; [E,256] intermediates never touch HBM.
// R13: node MLP fused into edge kernel via ticket ("last block of 32-node
// group"), but UNLIKE R11 no __threadfence(): partials move through the
// device coherence point with per-line agent-scope atomic store/load (SC1),
// ordering via the compiler's vmcnt(0)-before-s_barrier + device-scope
// atomicAdd ticket. No L2 writeback/invalidate => weight residency intact.

#define NN 384
#define VV 32
#define HH 128
#define UU 256
#define MM 64            // edges per block
#define NCHUNK 6         // 6*64 = 384 = 383 edges + 1 pad
#define SS 264           // LDS row stride edge buffers (256-wide, +8 pad)
#define XS 392           // node xs row stride (384-wide, +8 pad)

typedef __bf16 bf16v8 __attribute__((ext_vector_type(8)));
typedef __bf16 bf16v4 __attribute__((ext_vector_type(4)));
typedef float  f32x4  __attribute__((ext_vector_type(4)));
typedef float  f32x16 __attribute__((ext_vector_type(16)));

__device__ __forceinline__ float fast_rcp(float x) { return __builtin_amdgcn_rcpf(x); }
__device__ __forceinline__ float fast_sqrt(float x) { return __builtin_amdgcn_sqrtf(x); }
__device__ __forceinline__ float fast_silu(float v) {
    return v * __builtin_amdgcn_rcpf(1.f + __expf(-v));
}
// agent-scope (device) coherent store/load: per-line write-through /
// coherence-point read, NO cache maintenance (the R11 killer).
__device__ __forceinline__ void store_agent(float* p, float v) {
    __hip_atomic_store(p, v, __ATOMIC_RELAXED, __HIP_MEMORY_SCOPE_AGENT);
}
__device__ __forceinline__ float load_agent(const float* p) {
    return __hip_atomic_load(p, __ATOMIC_RELAXED, __HIP_MEMORY_SCOPE_AGENT);
}

// ---------------- weight repack, LDS-tiled transpose -----------------------
// 32-fmt (N=256 GEMMs): P[kt][n][kk] = W[kt*16+kk][n]*scale, kk<16.
// Also zeroes the 12 node-group ticket counters (re-poison safe).
__global__ __launch_bounds__(256)
void repack_all(const float* __restrict__ We1, const float* __restrict__ We2,
                const float* __restrict__ Wx1, const float* __restrict__ Wx2,
                const float* __restrict__ Wh1, const float* __restrict__ Wh2,
                const float* __restrict__ Wxl, const float* __restrict__ Whl,
                __bf16* __restrict__ we1p, __bf16* __restrict__ we2p,
                __bf16* __restrict__ wx1p, __bf16* __restrict__ wx2p,
                __bf16* __restrict__ wh1p, __bf16* __restrict__ wh2p,
                __bf16* __restrict__ wxlp, __bf16* __restrict__ whlp,
                unsigned* __restrict__ cnt) {
    const float s288 = 0.05892556509887896f;   // 1/sqrt(288)
    const float s384 = 0.05103103630798288f;   // 1/sqrt(384)
    const float s16  = 0.0625f;
    const int b   = blockIdx.x;
    const int tid = threadIdx.x;
    if (b == 0 && tid < 12) cnt[tid] = 0u;

    if (b < 212) {                               // ---- fmt32 transpose tiles
        __shared__ __bf16 T[32 * 72];
        const float* src; __bf16* dst; int tile; float scale;
        if (b < 36)       { src = We1; dst = we1p; tile = b;       scale = s288; }
        else if (b < 68)  { src = We2; dst = we2p; tile = b - 36;  scale = s16;  }
        else if (b < 100) { src = Wx1; dst = wx1p; tile = b - 68;  scale = s16;  }
        else if (b < 132) { src = Wx2; dst = wx2p; tile = b - 100; scale = s16;  }
        else if (b < 180) { src = Wh1; dst = wh1p; tile = b - 132; scale = s384; }
        else              { src = Wh2; dst = wh2p; tile = b - 180; scale = s16;  }
        const int kt0 = tile >> 2, nt0 = tile & 3;
        const int k0 = kt0 * 32, n0 = nt0 * 64;
#pragma unroll
        for (int i = 0; i < 8; ++i) {
            int p = tid + i * 256;
            int k = p >> 6, n = p & 63;
            T[k * 72 + n] = (__bf16)(src[(k0 + k) * 256 + n0 + n] * scale);
        }
        __syncthreads();
        const int ktl = tid >> 7, rem = tid & 127;
        const int n = rem >> 1, kh = rem & 1;
        bf16v8 v;
#pragma unroll
        for (int j = 0; j < 8; ++j)
            v[j] = T[(ktl * 16 + kh * 8 + j) * 72 + n];
        *(bf16v8*)(dst + (kt0 * 2 + ktl) * 4096 + (n0 + n) * 16 + kh * 8) = v;
        return;
    }
    // ---- scalar fmt16 region: Wxl (8192 el), Whl (32768 el) ----
    int t = (b - 212) * 256 + tid;
    const float* src; __bf16* dst; int Nout; int idx; float scale;
    if (t < 8192)       { src = Wxl; dst = wxlp; Nout = 32;  idx = t;        scale = 1.0f; }
    else if (t < 40960) { src = Whl; dst = whlp; Nout = 128; idx = t - 8192; scale = s16;  }
    else return;
    int kt  = idx / (Nout * 32);
    int rem = idx - kt * Nout * 32;
    int n   = rem >> 5;
    int kk  = rem & 31;
    dst[idx] = (__bf16)(src[(kt * 32 + kk) * Nout + n] * scale);
}

// ---- 64x256 GEMM: Y = silu(X @ Wp [+ cinit]), 8 waves, 32x32x16 MFMA ------
template <int KT>
__device__ __forceinline__ void gemm32(const __bf16* X, int xs,
                                       const __bf16* __restrict__ P,
                                       __bf16* Y, int ys,
                                       int wave, int lane, const float* cinit) {
    const int m  = lane & 31;
    const int kh = lane >> 5;
    float iv = cinit ? cinit[wave * 32 + m] : 0.f;
    f32x16 acc0, acc1;
#pragma unroll
    for (int i = 0; i < 16; ++i) { acc0[i] = iv; acc1[i] = iv; }
    const __bf16* xr = X + m * xs + kh * 8;
    const __bf16* pb = P + (wave * 32 + m) * 16 + kh * 8;
    bf16v8 b0 = *(const bf16v8*)(pb);
    bf16v8 b1 = (KT > 1) ? *(const bf16v8*)(pb + 4096) : b0;
#pragma unroll
    for (int kt = 0; kt < KT; ++kt) {
        bf16v8 a0 = *(const bf16v8*)(xr + kt * 16);
        bf16v8 a1 = *(const bf16v8*)(xr + 32 * xs + kt * 16);
        bf16v8 bn = (kt + 2 < KT) ? *(const bf16v8*)(pb + (kt + 2) * 4096) : b0;
        acc0 = __builtin_amdgcn_mfma_f32_32x32x16_bf16(a0, b0, acc0, 0, 0, 0);
        acc1 = __builtin_amdgcn_mfma_f32_32x32x16_bf16(a1, b0, acc1, 0, 0, 0);
        b0 = b1; b1 = bn;
    }
#pragma unroll
    for (int reg = 0; reg < 16; ++reg) {
        int row = (reg & 3) + 8 * (reg >> 2) + 4 * kh;
        Y[row * ys + wave * 32 + m]        = (__bf16)fast_silu(acc0[reg]);
        Y[(32 + row) * ys + wave * 32 + m] = (__bf16)fast_silu(acc1[reg]);
    }
}

// ---- 32x256 GEMM (single m-tile): Y = silu(X @ Wp), 8 waves ---------------
template <int KT>
__device__ __forceinline__ void gemmS(const __bf16* X, int xs,
                                      const __bf16* __restrict__ P,
                                      __bf16* Y, int ys, int wave, int lane) {
    const int m  = lane & 31;
    const int kh = lane >> 5;
    f32x16 acc = {};
    const __bf16* xr = X + m * xs + kh * 8;
    const __bf16* pb = P + (wave * 32 + m) * 16 + kh * 8;
    bf16v8 b0 = *(const bf16v8*)(pb);
    bf16v8 b1 = (KT > 1) ? *(const bf16v8*)(pb + 4096) : b0;
#pragma unroll
    for (int kt = 0; kt < KT; ++kt) {
        bf16v8 a0 = *(const bf16v8*)(xr + kt * 16);
        bf16v8 bn = (kt + 2 < KT) ? *(const bf16v8*)(pb + (kt + 2) * 4096) : b0;
        acc = __builtin_amdgcn_mfma_f32_32x32x16_bf16(a0, b0, acc, 0, 0, 0);
        b0 = b1; b1 = bn;
    }
#pragma unroll
    for (int reg = 0; reg < 16; ++reg) {
        int row = (reg & 3) + 8 * (reg >> 2) + 4 * kh;
        Y[row * ys + wave * 32 + m] = (__bf16)fast_silu(acc[reg]);
    }
}

// ------------- fused edge kernel (+ ticketed node epilogue) ----------------
__global__ __launch_bounds__(512, 4)
void edge_kernel(const float* __restrict__ nv, const float* __restrict__ nf,
                 const __bf16* __restrict__ we1p, const __bf16* __restrict__ we2p,
                 const __bf16* __restrict__ wx1p, const __bf16* __restrict__ wx2p,
                 const __bf16* __restrict__ wxlp, const float* __restrict__ bxl,
                 const float* __restrict__ winf,
                 const __bf16* __restrict__ wh1p, const __bf16* __restrict__ wh2p,
                 const __bf16* __restrict__ whlp,
                 float* __restrict__ shiftp, float* __restrict__ mip,
                 unsigned* __restrict__ cnt, float* __restrict__ out) {
    __shared__ __align__(16) __bf16 Ab[MM * SS];   // ef -> m -> t2 -> spart -> xsb
    __shared__ __align__(16) __bf16 Bb[MM * SS];   // h1 -> scratch -> t1 -> phix -> h1b|h2b
    __shared__ float gateb[MM];
    __shared__ float cvec[UU];     // nf[r] @ We1'[160:288]  (block-constant)
    __shared__ float nfr[HH];
    __shared__ unsigned ticket;

    float* Bf = (float*)Bb;
    float* Af = (float*)Ab;

    const int tid  = threadIdx.x;
    const int wave = tid >> 6;
    const int lane = tid & 63;
    const int col  = lane & 15;
    const int q    = lane >> 4;
    const int r     = blockIdx.y;
    const int chunk = blockIdx.x;
    const int e0    = chunk * MM;

    // ---- stage: nfr, len2 (cols 0..31), nf[s] (cols 32..159) ----
    if (tid < HH) nfr[tid] = nf[r * HH + tid];
#pragma unroll
    for (int p = tid; p < MM * 32; p += 512) {
        int i = p >> 5, v = p & 31;
        int s = r + 1 + e0 + i; if (s >= NN) s -= NN;
        const float* pr = nv + (r * 32 + v) * 3;
        const float* ps = nv + (s * 32 + v) * 3;
        float d0 = pr[0] - ps[0];
        float d1 = pr[1] - ps[1];
        float d2 = pr[2] - ps[2];
        Ab[i * SS + v] = (__bf16)(d0 * d0 + d1 * d1 + d2 * d2);
    }
#pragma unroll
    for (int p = tid; p < MM * 32; p += 512) {
        int i = p >> 5, hc = (p & 31) << 2;
        int s = r + 1 + e0 + i; if (s >= NN) s -= NN;
        float4 fs = *(const float4*)(nf + s * HH + hc);
        bf16v4 bs = { (__bf16)fs.x, (__bf16)fs.y, (__bf16)fs.z, (__bf16)fs.w };
        *(bf16v4*)&Ab[i * SS + 32 + hc] = bs;
    }
    __syncthreads();

    // ---- cvec[n] = sum_k nfr[k] * We1'[160+k][n]  (kt16 = 10..17) ----
    if (tid < UU) {
        float c = 0.f;
#pragma unroll
        for (int kt = 10; kt < 18; ++kt) {
            const __bf16* wrow = we1p + kt * 4096 + tid * 16;
#pragma unroll
            for (int kk = 0; kk < 16; ++kk)
                c += (float)wrow[kk] * nfr[(kt - 10) * 16 + kk];
        }
        cvec[tid] = c;
    }
    __syncthreads();

    // ---- h1 = silu(ef @ We1'[0:160] + cvec) : A -> B ----
    gemm32<10>(Ab, SS, we1p, Bb, SS, wave, lane, cvec);
    __syncthreads();
    // ---- m = silu(h1 @ We2') : B -> A ----
    gemm32<16>(Bb, SS, we2p, Ab, SS, wave, lane, nullptr);
    __syncthreads();

    // ---- gate e = sigmoid(m @ Winf / 16); partials in B scratch ----
    {
        int i = tid >> 3, kq = (tid & 7) * 32;
        const __bf16* mrow = Ab + i * SS + kq;
        const float*  wrow = winf + kq;
        float g = 0.f;
#pragma unroll
        for (int k = 0; k < 32; ++k)
            g += (float)mrow[k] * wrow[k];
        Bf[tid] = g;
    }
    __syncthreads();
    if (tid < MM) {
        float g = 0.f;
#pragma unroll
        for (int p8 = 0; p8 < 8; ++p8) g += Bf[tid * 8 + p8];
        gateb[tid] = (e0 + tid == NN - 1) ? 0.f     // self-edge pad
                                          : fast_rcp(1.f + __expf(-g * 0.0625f));
    }
    __syncthreads();

    // ---- m_i partials -> agent store (device-visible, no cache flush) ----
    {
        int c = tid & 255, ih = (tid >> 8) * 32;
        const __bf16* mcol = Ab + ih * SS + c;
        const float*  gp   = gateb + ih;
        float mp = 0.f;
#pragma unroll
        for (int i = 0; i < 32; ++i)
            mp += (float)mcol[i * SS] * gp[i];
        Bf[tid] = mp;
    }
    __syncthreads();
    if (tid < 256)
        store_agent(&mip[(r * NCHUNK + chunk) * UU + tid], Bf[tid] + Bf[256 + tid]);
    __syncthreads();

    // ---- t1 = silu(m @ Wx1'): A -> B ; t2 = silu(t1 @ Wx2'): B -> A ----
    gemm32<16>(Ab, SS, wx1p, Bb, SS, wave, lane, nullptr);
    __syncthreads();
    gemm32<16>(Bb, SS, wx2p, Ab, SS, wave, lane, nullptr);
    __syncthreads();

    // ---- phi_x = t2 @ Wxl + bxl : A -> Bf (f32, 64x32); 16x16 MFMA ----
    {
        int mt = wave >> 1, nt = wave & 1;
        float bias = bxl[nt * 16 + col];
        f32x4 acc = {bias, bias, bias, bias};
        const __bf16* xr = Ab + (mt * 16 + col) * SS + q * 8;
#pragma unroll
        for (int kt = 0; kt < 8; ++kt) {
            bf16v8 a = *(const bf16v8*)(xr + kt * 32);
            bf16v8 b = *(const bf16v8*)(wxlp + kt * 1024 + (nt * 16 + col) * 32 + q * 8);
            acc = __builtin_amdgcn_mfma_f32_16x16x32_bf16(a, b, acc, 0, 0, 0);
        }
#pragma unroll
        for (int i = 0; i < 4; ++i)
            Bf[(mt * 16 + q * 4 + i) * 32 + nt * 16 + col] = acc[i];
    }
    __syncthreads();

    // ---- fold 1/(1+len) into phix: one norm per (edge, v) ----
    {
        int v = tid & 31;
        float r0 = nv[(r * 32 + v) * 3 + 0];
        float r1 = nv[(r * 32 + v) * 3 + 1];
        float r2 = nv[(r * 32 + v) * 3 + 2];
#pragma unroll
        for (int p = tid; p < MM * 32; p += 512) {
            int i = p >> 5;
            int s = r + 1 + e0 + i; if (s >= NN) s -= NN;
            const float* ps = nv + (s * 32 + v) * 3;
            float d0 = r0 - ps[0], d1 = r1 - ps[1], d2 = r2 - ps[2];
            float len = fast_sqrt(fmaxf(d0 * d0 + d1 * d1 + d2 * d2, 1e-20f));
            Bf[p] *= fast_rcp(1.f + len);
        }
    }
    __syncthreads();

    // ---- shift partials: tid<384 -> (g16, sv, sc), 16 edges each ----
    if (tid < 384) {
        int g16 = tid / 96, rem = tid % 96;
        int sv = rem / 3, sc = rem - sv * 3;
        float rc = nv[(r * 32 + sv) * 3 + sc];
        float sp = 0.f;
#pragma unroll
        for (int i = g16 * 16; i < g16 * 16 + 16; ++i) {
            int s = r + 1 + e0 + i; if (s >= NN) s -= NN;
            float d = rc - nv[(s * 32 + sv) * 3 + sc];
            sp += Bf[i * 32 + sv] * d;
        }
        Af[tid] = sp;
    }
    __syncthreads();
    if (tid < 96)
        store_agent(&shiftp[(r * NCHUNK + chunk) * 96 + tid],
                    Af[tid] + Af[96 + tid] + Af[192 + tid] + Af[288 + tid]);

    // ==== ticket: last block of the 32-node group runs the node MLP ========
    // barrier's vmcnt(0) drains the agent stores (device-visible) first.
    __syncthreads();
    if (tid == 0) ticket = atomicAdd(&cnt[r >> 5], 1u);
    __syncthreads();
    if (ticket != 192u - 1u) return;

    const int n0 = (r >> 5) * 32;
    __bf16* xsb = Ab;                       // 32*XS = 25088 B <= 33792 B
    __bf16* h1b = Bb;                       // 32*SS = 16896 B
    __bf16* h2b = Bb + 32 * SS;             // second half of Bb

    // ---- reduce chunk partials (agent loads); stage nf; vectors_out ----
#pragma unroll
    for (int p = tid; p < 32 * 256; p += 512) {
        int i = p >> 8, c = p & 255;
        float a = 0.f;
#pragma unroll
        for (int ch = 0; ch < NCHUNK; ++ch)
            a += load_agent(&mip[((n0 + i) * NCHUNK + ch) * UU + c]);
        xsb[i * XS + c] = (__bf16)a;
    }
#pragma unroll
    for (int p = tid; p < 32 * 128; p += 512) {
        int i = p >> 7, c = p & 127;
        xsb[i * XS + 256 + c] = (__bf16)nf[(n0 + i) * HH + c];
    }
#pragma unroll
    for (int p = tid; p < 32 * 96; p += 512) {
        int i = p / 96, j = p - i * 96;
        float s = 0.f;
#pragma unroll
        for (int ch = 0; ch < NCHUNK; ++ch)
            s += load_agent(&shiftp[((n0 + i) * NCHUNK + ch) * 96 + j]);
        out[(n0 + i) * 96 + j] = nv[(n0 + i) * 96 + j] + s * (1.f / 383.f);
    }
    __syncthreads();

    // ---- h1 = silu(xs @ Wh1') ; h2 = silu(h1 @ Wh2') ----
    gemmS<24>(xsb, XS, wh1p, h1b, SS, wave, lane);
    __syncthreads();
    gemmS<16>(h1b, SS, wh2p, h2b, SS, wave, lane);
    __syncthreads();

    // ---- features_out = h2 @ Whl' + nf  (N=128, 16x16 MFMA, 8 n-tiles) ----
    {
        int n = wave * 16 + col;
#pragma unroll
        for (int mt = 0; mt < 2; ++mt) {
            f32x4 acc = {0.f, 0.f, 0.f, 0.f};
            const __bf16* xr = h2b + (mt * 16 + col) * SS + q * 8;
#pragma unroll
            for (int kt = 0; kt < 8; ++kt) {
                bf16v8 a = *(const bf16v8*)(xr + kt * 32);
                bf16v8 b = *(const bf16v8*)(whlp + kt * 4096 + n * 32 + q * 8);
                acc = __builtin_amdgcn_mfma_f32_16x16x32_bf16(a, b, acc, 0, 0, 0);
            }
#pragma unroll
            for (int i = 0; i < 4; ++i) {
                int row = n0 + mt * 16 + q * 4 + i;
                out[NN * 96 + row * HH + n] = acc[i] + nf[row * HH + n];
            }
        }
    }
}

// ------------------------------- launcher ----------------------------------
extern "C" void kernel_launch(void* const* d_in, const int* in_sizes, int n_in,
                              void* d_out, int out_size, void* d_ws, size_t ws_size,
                              hipStream_t stream) {
    const float* nv   = (const float*)d_in[0];
    const float* nf   = (const float*)d_in[1];
    const float* We1  = (const float*)d_in[2];
    const float* We2  = (const float*)d_in[3];
    const float* Wx1  = (const float*)d_in[4];
    const float* Wx2  = (const float*)d_in[5];
    const float* Wxl  = (const float*)d_in[6];
    const float* bxl  = (const float*)d_in[7];
    const float* Winf = (const float*)d_in[8];
    const float* Wh1  = (const float*)d_in[9];
    const float* Wh2  = (const float*)d_in[10];
    const float* Whl  = (const float*)d_in[11];
    float* out = (float*)d_out;

    char* ws = (char*)d_ws;
    float*    mip    = (float*)ws;                      // 384*6*256*4 = 2359296
    float*    shiftp = (float*)(ws + 2359296);          // 384*6*96*4  =  884736
    __bf16*   we1p   = (__bf16*)(ws + 3244032);         // 147456
    __bf16*   we2p   = (__bf16*)(ws + 3391488);         // 131072
    __bf16*   wx1p   = (__bf16*)(ws + 3522560);         // 131072
    __bf16*   wx2p   = (__bf16*)(ws + 3653632);         // 131072
    __bf16*   wh1p   = (__bf16*)(ws + 3784704);         // 196608
    __bf16*   wh2p   = (__bf16*)(ws + 3981312);         // 131072
    __bf16*   wxlp   = (__bf16*)(ws + 4112384);         // 16384
    __bf16*   whlp   = (__bf16*)(ws + 4128768);         // 65536
    unsigned* cnt    = (unsigned*)(ws + 4194304);       // 48

    repack_all<<<dim3(372), 256, 0, stream>>>(We1, We2, Wx1, Wx2, Wh1, Wh2, Wxl, Whl,
                                              we1p, we2p, wx1p, wx2p,
                                              wh1p, wh2p, wxlp, whlp, cnt);

    edge_kernel<<<dim3(NCHUNK, NN), 512, 0, stream>>>(nv, nf, we1p, we2p, wx1p, wx2p,
                                                      wxlp, bxl, Winf,
                                                      wh1p, wh2p, whlp,
                                                      shiftp, mip, cnt, out);
}

// Round 14
// 205.883 us; speedup vs baseline: 1.1114x; 1.1114x over previous
//
#include <hip/hip_runtime.h>
#include <hip/hip_bf16.h>

// EGCL (EGNN layer): N=384 nodes, V=32 vectors, H=128 feats, U=256 width.
// E = N*(N-1) = 147072 fully-connected edges. f32 in/out, bf16 MFMA compute.
// Edges grouped by RECEIVER r (s=(r+1+j')%N): segment sums are in-block
// reductions; [E,256] intermediates never touch HBM.
// R14 (R12 base; fusion abandoned after R11/R13): edge barriers 13->9
// (shfl gate reduce, atomicAdd m_i/shift overlap next gemm, fold merged
// into phix epilogue); cvec precomputed in repack; mi/shift accumulated
// directly (zeroed in repack) so node staging is 1 read/element not 6.

#define NN 384
#define VV 32
#define HH 128
#define UU 256
#define MM 64            // edges per block
#define NCHUNK 6         // 6*64 = 384 = 383 edges + 1 pad
#define SS 264           // LDS row stride edge buffers (256-wide, +8 pad)
#define XS 392           // node xs row stride (384-wide, +8 pad)

typedef __bf16 bf16v8 __attribute__((ext_vector_type(8)));
typedef __bf16 bf16v4 __attribute__((ext_vector_type(4)));
typedef float  f32x4  __attribute__((ext_vector_type(4)));
typedef float  f32x16 __attribute__((ext_vector_type(16)));

__device__ __forceinline__ float fast_rcp(float x) { return __builtin_amdgcn_rcpf(x); }
__device__ __forceinline__ float fast_sqrt(float x) { return __builtin_amdgcn_sqrtf(x); }
__device__ __forceinline__ float fast_silu(float v) {
    return v * __builtin_amdgcn_rcpf(1.f + __expf(-v));
}

// ---------------- repack + cvec + accumulator zeroing ----------------------
// blocks [0,212): fmt32 LDS-tiled transpose  P[kt][n][kk]=W[kt*16+kk][n]*s
// blocks [212,372): scalar fmt16 (Wxl, Whl)
// blocks [372,756): cvecg[r][n] = sum_k nf[r][k]*We1[160+k][n]*s288
// blocks [756,888): zero mi[384*256]+shift[384*96] (float4 stores)
__global__ __launch_bounds__(256)
void repack_all(const float* __restrict__ We1, const float* __restrict__ We2,
                const float* __restrict__ Wx1, const float* __restrict__ Wx2,
                const float* __restrict__ Wh1, const float* __restrict__ Wh2,
                const float* __restrict__ Wxl, const float* __restrict__ Whl,
                const float* __restrict__ nf,
                __bf16* __restrict__ we1p, __bf16* __restrict__ we2p,
                __bf16* __restrict__ wx1p, __bf16* __restrict__ wx2p,
                __bf16* __restrict__ wh1p, __bf16* __restrict__ wh2p,
                __bf16* __restrict__ wxlp, __bf16* __restrict__ whlp,
                float* __restrict__ cvecg, float* __restrict__ zbase) {
    const float s288 = 0.05892556509887896f;   // 1/sqrt(288)
    const float s384 = 0.05103103630798288f;   // 1/sqrt(384)
    const float s16  = 0.0625f;
    const int b   = blockIdx.x;
    const int tid = threadIdx.x;

    if (b < 212) {                               // ---- fmt32 transpose tiles
        __shared__ __bf16 T[32 * 72];
        const float* src; __bf16* dst; int tile; float scale;
        if (b < 36)       { src = We1; dst = we1p; tile = b;       scale = s288; }
        else if (b < 68)  { src = We2; dst = we2p; tile = b - 36;  scale = s16;  }
        else if (b < 100) { src = Wx1; dst = wx1p; tile = b - 68;  scale = s16;  }
        else if (b < 132) { src = Wx2; dst = wx2p; tile = b - 100; scale = s16;  }
        else if (b < 180) { src = Wh1; dst = wh1p; tile = b - 132; scale = s384; }
        else              { src = Wh2; dst = wh2p; tile = b - 180; scale = s16;  }
        const int kt0 = tile >> 2, nt0 = tile & 3;
        const int k0 = kt0 * 32, n0 = nt0 * 64;
#pragma unroll
        for (int i = 0; i < 8; ++i) {
            int p = tid + i * 256;
            int k = p >> 6, n = p & 63;
            T[k * 72 + n] = (__bf16)(src[(k0 + k) * 256 + n0 + n] * scale);
        }
        __syncthreads();
        const int ktl = tid >> 7, rem = tid & 127;
        const int n = rem >> 1, kh = rem & 1;
        bf16v8 v;
#pragma unroll
        for (int j = 0; j < 8; ++j)
            v[j] = T[(ktl * 16 + kh * 8 + j) * 72 + n];
        *(bf16v8*)(dst + (kt0 * 2 + ktl) * 4096 + (n0 + n) * 16 + kh * 8) = v;
        return;
    }
    if (b < 372) {      // ---- scalar fmt16: Wxl (8192 el), Whl (32768 el)
        int t = (b - 212) * 256 + tid;
        const float* src; __bf16* dst; int Nout; int idx; float scale;
        if (t < 8192)       { src = Wxl; dst = wxlp; Nout = 32;  idx = t;        scale = 1.0f; }
        else if (t < 40960) { src = Whl; dst = whlp; Nout = 128; idx = t - 8192; scale = s16;  }
        else return;
        int kt  = idx / (Nout * 32);
        int rem = idx - kt * Nout * 32;
        int n   = rem >> 5;
        int kk  = rem & 31;
        dst[idx] = (__bf16)(src[(kt * 32 + kk) * Nout + n] * scale);
        return;
    }
    if (b < 756) {      // ---- cvecg: per-receiver constant term of gemm1
        int r = b - 372;
        float a = 0.f;
#pragma unroll 4
        for (int k = 0; k < 128; ++k)
            a += nf[r * HH + k] * We1[(160 + k) * 256 + tid];
        cvecg[r * UU + tid] = a * s288;
        return;
    }
    // ---- zero accumulators: 33792 float4 = mi + shift ----
    ((f32x4*)zbase)[(b - 756) * 256 + tid] = (f32x4){0.f, 0.f, 0.f, 0.f};
}

// ---- 64x256 GEMM: Y = silu(X @ Wp [+ cinit]), 8 waves, 32x32x16 MFMA ------
template <int KT>
__device__ __forceinline__ void gemm32(const __bf16* X, int xs,
                                       const __bf16* __restrict__ P,
                                       __bf16* Y, int ys,
                                       int wave, int lane, const float* cinit) {
    const int m  = lane & 31;
    const int kh = lane >> 5;
    float iv = cinit ? cinit[wave * 32 + m] : 0.f;
    f32x16 acc0, acc1;
#pragma unroll
    for (int i = 0; i < 16; ++i) { acc0[i] = iv; acc1[i] = iv; }
    const __bf16* xr = X + m * xs + kh * 8;
    const __bf16* pb = P + (wave * 32 + m) * 16 + kh * 8;
    bf16v8 b0 = *(const bf16v8*)(pb);
    bf16v8 b1 = (KT > 1) ? *(const bf16v8*)(pb + 4096) : b0;
#pragma unroll
    for (int kt = 0; kt < KT; ++kt) {
        bf16v8 a0 = *(const bf16v8*)(xr + kt * 16);
        bf16v8 a1 = *(const bf16v8*)(xr + 32 * xs + kt * 16);
        bf16v8 bn = (kt + 2 < KT) ? *(const bf16v8*)(pb + (kt + 2) * 4096) : b0;
        acc0 = __builtin_amdgcn_mfma_f32_32x32x16_bf16(a0, b0, acc0, 0, 0, 0);
        acc1 = __builtin_amdgcn_mfma_f32_32x32x16_bf16(a1, b0, acc1, 0, 0, 0);
        b0 = b1; b1 = bn;
    }
#pragma unroll
    for (int reg = 0; reg < 16; ++reg) {
        int row = (reg & 3) + 8 * (reg >> 2) + 4 * kh;
        Y[row * ys + wave * 32 + m]        = (__bf16)fast_silu(acc0[reg]);
        Y[(32 + row) * ys + wave * 32 + m] = (__bf16)fast_silu(acc1[reg]);
    }
}

// ---- 32x256 GEMM (single m-tile): Y = silu(X @ Wp), 8 waves ---------------
template <int KT>
__device__ __forceinline__ void gemmS(const __bf16* X, int xs,
                                      const __bf16* __restrict__ P,
                                      __bf16* Y, int ys, int wave, int lane) {
    const int m  = lane & 31;
    const int kh = lane >> 5;
    f32x16 acc = {};
    const __bf16* xr = X + m * xs + kh * 8;
    const __bf16* pb = P + (wave * 32 + m) * 16 + kh * 8;
    bf16v8 b0 = *(const bf16v8*)(pb);
    bf16v8 b1 = (KT > 1) ? *(const bf16v8*)(pb + 4096) : b0;
#pragma unroll
    for (int kt = 0; kt < KT; ++kt) {
        bf16v8 a0 = *(const bf16v8*)(xr + kt * 16);
        bf16v8 bn = (kt + 2 < KT) ? *(const bf16v8*)(pb + (kt + 2) * 4096) : b0;
        acc = __builtin_amdgcn_mfma_f32_32x32x16_bf16(a0, b0, acc, 0, 0, 0);
        b0 = b1; b1 = bn;
    }
#pragma unroll
    for (int reg = 0; reg < 16; ++reg) {
        int row = (reg & 3) + 8 * (reg >> 2) + 4 * kh;
        Y[row * ys + wave * 32 + m] = (__bf16)fast_silu(acc[reg]);
    }
}

// --------------------------- fused edge kernel -----------------------------
__global__ __launch_bounds__(512, 4)
void edge_kernel(const float* __restrict__ nv, const float* __restrict__ nf,
                 const __bf16* __restrict__ we1p, const __bf16* __restrict__ we2p,
                 const __bf16* __restrict__ wx1p, const __bf16* __restrict__ wx2p,
                 const __bf16* __restrict__ wxlp, const float* __restrict__ bxl,
                 const float* __restrict__ winf, const float* __restrict__ cvecg,
                 float* __restrict__ shift, float* __restrict__ mi) {
    __shared__ __align__(16) __bf16 Ab[MM * SS];   // ef -> m -> t2
    __shared__ __align__(16) __bf16 Bb[MM * SS];   // h1 -> t1 -> phix(f32)
    __shared__ float gateb[MM];

    float* Bf = (float*)Bb;

    const int tid  = threadIdx.x;
    const int wave = tid >> 6;
    const int lane = tid & 63;
    const int col  = lane & 15;
    const int q    = lane >> 4;
    const int r     = blockIdx.y;
    const int chunk = blockIdx.x;
    const int e0    = chunk * MM;

    // ---- stage: len2 (cols 0..31), nf[s] (cols 32..159) ----
#pragma unroll
    for (int p = tid; p < MM * 32; p += 512) {
        int i = p >> 5, v = p & 31;
        int s = r + 1 + e0 + i; if (s >= NN) s -= NN;
        const float* pr = nv + (r * 32 + v) * 3;
        const float* ps = nv + (s * 32 + v) * 3;
        float d0 = pr[0] - ps[0];
        float d1 = pr[1] - ps[1];
        float d2 = pr[2] - ps[2];
        Ab[i * SS + v] = (__bf16)(d0 * d0 + d1 * d1 + d2 * d2);
    }
#pragma unroll
    for (int p = tid; p < MM * 32; p += 512) {
        int i = p >> 5, hc = (p & 31) << 2;
        int s = r + 1 + e0 + i; if (s >= NN) s -= NN;
        float4 fs = *(const float4*)(nf + s * HH + hc);
        bf16v4 bs = { (__bf16)fs.x, (__bf16)fs.y, (__bf16)fs.z, (__bf16)fs.w };
        *(bf16v4*)&Ab[i * SS + 32 + hc] = bs;
    }
    __syncthreads();                                                   // B1

    // ---- h1 = silu(ef @ We1'[0:160] + cvecg[r]) : A -> B ----
    gemm32<10>(Ab, SS, we1p, Bb, SS, wave, lane, cvecg + r * UU);
    __syncthreads();                                                   // B2
    // ---- m = silu(h1 @ We2') : B -> A ----
    gemm32<16>(Bb, SS, we2p, Ab, SS, wave, lane, nullptr);
    __syncthreads();                                                   // B3

    // ---- gate e = sigmoid(m @ Winf / 16); 8-lane shfl reduce ----
    {
        int i = tid >> 3, kq = (tid & 7) * 32;
        const __bf16* mrow = Ab + i * SS + kq;
        const float*  wrow = winf + kq;
        float g = 0.f;
#pragma unroll
        for (int k = 0; k < 32; ++k)
            g += (float)mrow[k] * wrow[k];
        g += __shfl_xor(g, 1);
        g += __shfl_xor(g, 2);
        g += __shfl_xor(g, 4);
        if ((tid & 7) == 0)
            gateb[i] = (e0 + i == NN - 1) ? 0.f     // self-edge pad
                                          : fast_rcp(1.f + __expf(-g * 0.0625f));
    }
    __syncthreads();                                                   // B4

    // ---- m_i partials -> atomicAdd (overlaps gemm3; no barrier) ----
    {
        int c = tid & 255, ih = (tid >> 8) * 32;
        const __bf16* mcol = Ab + ih * SS + c;
        const float*  gp   = gateb + ih;
        float mp = 0.f;
#pragma unroll
        for (int i = 0; i < 32; ++i)
            mp += (float)mcol[i * SS] * gp[i];
        atomicAdd(&mi[r * UU + c], mp);
    }

    // ---- t1 = silu(m @ Wx1'): A -> B ; t2 = silu(t1 @ Wx2'): B -> A ----
    gemm32<16>(Ab, SS, wx1p, Bb, SS, wave, lane, nullptr);
    __syncthreads();                                                   // B5
    gemm32<16>(Bb, SS, wx2p, Ab, SS, wave, lane, nullptr);
    __syncthreads();                                                   // B6

    // ---- phi_x = (t2 @ Wxl + bxl) * 1/(1+len) : A -> Bf (fold fused) ----
    {
        int mt = wave >> 1, nt = wave & 1;
        int v = nt * 16 + col;
        float bias = bxl[v];
        f32x4 acc = {bias, bias, bias, bias};
        const __bf16* xr = Ab + (mt * 16 + col) * SS + q * 8;
#pragma unroll
        for (int kt = 0; kt < 8; ++kt) {
            bf16v8 a = *(const bf16v8*)(xr + kt * 32);
            bf16v8 b = *(const bf16v8*)(wxlp + kt * 1024 + v * 32 + q * 8);
            acc = __builtin_amdgcn_mfma_f32_16x16x32_bf16(a, b, acc, 0, 0, 0);
        }
        float r0 = nv[(r * 32 + v) * 3 + 0];
        float r1 = nv[(r * 32 + v) * 3 + 1];
        float r2 = nv[(r * 32 + v) * 3 + 2];
#pragma unroll
        for (int i = 0; i < 4; ++i) {
            int e = mt * 16 + q * 4 + i;
            int s = r + 1 + e0 + e; if (s >= NN) s -= NN;
            const float* ps = nv + (s * 32 + v) * 3;
            float d0 = r0 - ps[0], d1 = r1 - ps[1], d2 = r2 - ps[2];
            float len = fast_sqrt(fmaxf(d0 * d0 + d1 * d1 + d2 * d2, 1e-20f));
            Bf[e * 32 + v] = acc[i] * fast_rcp(1.f + len);
        }
    }
    __syncthreads();                                                   // B7

    // ---- shift partials: tid<384 -> (g16, sv, sc); atomicAdd ----
    if (tid < 384) {
        int g16 = tid / 96, rem = tid % 96;
        int sv = rem / 3, sc = rem - sv * 3;
        float rc = nv[(r * 32 + sv) * 3 + sc];
        float sp = 0.f;
#pragma unroll
        for (int i = g16 * 16; i < g16 * 16 + 16; ++i) {
            int s = r + 1 + e0 + i; if (s >= NN) s -= NN;
            float d = rc - nv[(s * 32 + sv) * 3 + sc];
            sp += Bf[i * 32 + sv] * d;
        }
        atomicAdd(&shift[r * 96 + rem], sp);
    }
}

// ---------------- node MLP (12 blocks x 32 rows) ---------------------------
__global__ __launch_bounds__(512)
void node_kernel(const float* __restrict__ nv, const float* __restrict__ nf,
                 const __bf16* __restrict__ wh1p, const __bf16* __restrict__ wh2p,
                 const __bf16* __restrict__ whlp,
                 const float* __restrict__ shift, const float* __restrict__ mi,
                 float* __restrict__ out) {
    __shared__ __align__(16) __bf16 xsb[32 * XS];   // [m_i | nf] 32x384
    __shared__ __align__(16) __bf16 h1b[32 * SS];
    __shared__ __align__(16) __bf16 h2b[32 * SS];
    const int tid  = threadIdx.x;
    const int wave = tid >> 6;
    const int lane = tid & 63;
    const int n0   = blockIdx.x * 32;

    // ---- stage xs = [m_i | nf]; vectors_out ----
#pragma unroll
    for (int p = tid; p < 32 * 256; p += 512) {
        int i = p >> 8, c = p & 255;
        xsb[i * XS + c] = (__bf16)mi[(n0 + i) * UU + c];
    }
#pragma unroll
    for (int p = tid; p < 32 * 128; p += 512) {
        int i = p >> 7, c = p & 127;
        xsb[i * XS + 256 + c] = (__bf16)nf[(n0 + i) * HH + c];
    }
#pragma unroll
    for (int p = tid; p < 32 * 96; p += 512) {
        int i = p / 96, j = p - i * 96;
        out[(n0 + i) * 96 + j] = nv[(n0 + i) * 96 + j]
                                 + shift[(n0 + i) * 96 + j] * (1.f / 383.f);
    }
    __syncthreads();

    // ---- h1 = silu(xs @ Wh1') ; h2 = silu(h1 @ Wh2') ----
    gemmS<24>(xsb, XS, wh1p, h1b, SS, wave, lane);
    __syncthreads();
    gemmS<16>(h1b, SS, wh2p, h2b, SS, wave, lane);
    __syncthreads();

    // ---- features_out = h2 @ Whl' + nf  (N=128, 16x16 MFMA, 8 n-tiles) ----
    {
        int col = lane & 15, q = lane >> 4;
        int n = wave * 16 + col;
#pragma unroll
        for (int mt = 0; mt < 2; ++mt) {
            f32x4 acc = {0.f, 0.f, 0.f, 0.f};
            const __bf16* xr = h2b + (mt * 16 + col) * SS + q * 8;
#pragma unroll
            for (int kt = 0; kt < 8; ++kt) {
                bf16v8 a = *(const bf16v8*)(xr + kt * 32);
                bf16v8 b = *(const bf16v8*)(whlp + kt * 4096 + n * 32 + q * 8);
                acc = __builtin_amdgcn_mfma_f32_16x16x32_bf16(a, b, acc, 0, 0, 0);
            }
#pragma unroll
            for (int i = 0; i < 4; ++i) {
                int row = n0 + mt * 16 + q * 4 + i;
                out[NN * 96 + row * HH + n] = acc[i] + nf[row * HH + n];
            }
        }
    }
}

// ------------------------------- launcher ----------------------------------
extern "C" void kernel_launch(void* const* d_in, const int* in_sizes, int n_in,
                              void* d_out, int out_size, void* d_ws, size_t ws_size,
                              hipStream_t stream) {
    const float* nv   = (const float*)d_in[0];
    const float* nf   = (const float*)d_in[1];
    const float* We1  = (const float*)d_in[2];
    const float* We2  = (const float*)d_in[3];
    const float* Wx1  = (const float*)d_in[4];
    const float* Wx2  = (const float*)d_in[5];
    const float* Wxl  = (const float*)d_in[6];
    const float* bxl  = (const float*)d_in[7];
    const float* Winf = (const float*)d_in[8];
    const float* Wh1  = (const float*)d_in[9];
    const float* Wh2  = (const float*)d_in[10];
    const float* Whl  = (const float*)d_in[11];
    float* out = (float*)d_out;

    char* ws = (char*)d_ws;
    float*  mi     = (float*)ws;                        // 384*256*4 = 393216
    float*  shift  = (float*)(ws + 393216);             // 384*96*4  = 147456
    float*  cvecg  = (float*)(ws + 540672);             // 384*256*4 = 393216
    __bf16* we1p   = (__bf16*)(ws + 933888);            // 147456
    __bf16* we2p   = (__bf16*)(ws + 1081344);           // 131072
    __bf16* wx1p   = (__bf16*)(ws + 1212416);           // 131072
    __bf16* wx2p   = (__bf16*)(ws + 1343488);           // 131072
    __bf16* wh1p   = (__bf16*)(ws + 1474560);           // 196608
    __bf16* wh2p   = (__bf16*)(ws + 1671168);           // 131072
    __bf16* wxlp   = (__bf16*)(ws + 1802240);           // 16384
    __bf16* whlp   = (__bf16*)(ws + 1818624);           // 65536

    repack_all<<<dim3(888), 256, 0, stream>>>(We1, We2, Wx1, Wx2, Wh1, Wh2, Wxl, Whl,
                                              nf, we1p, we2p, wx1p, wx2p,
                                              wh1p, wh2p, wxlp, whlp, cvecg, mi);

    edge_kernel<<<dim3(NCHUNK, NN), 512, 0, stream>>>(nv, nf, we1p, we2p, wx1p, wx2p,
                                                      wxlp, bxl, Winf, cvecg,
                                                      shift, mi);
    node_kernel<<<dim3(12), 512, 0, stream>>>(nv, nf, wh1p, wh2p, whlp,
                                              shift, mi, out);
}